// Round 4
// baseline (224.985 us; speedup 1.0000x reference)
//
#include <hip/hip_runtime.h>

// SoftPerspectiveShader: barycentric texture sampling + softmax RGB blend.
// N=4, H=W=512, K=8, F=200000.
//
// R1: gate face_colors gather on weight magnitude (zbuf sorted ->
//     exp((zinv-zmax)/1e-4) underflows unless within ~1.2e-3 of zmax).
// R2/R3: nontemporal streams, deferred bary, VGPR 28 -> 65 us, 2.8 TB/s,
//     VALU 10-12%, occ 65%. Traffic near-minimal (157-168 MB).
// R4: early-gather restructure -> NEUTRAL (compiler already had that
//     schedule; vmcnt is in-order and p2f was issued first).
// R5 (this round): TWO PIXELS PER THREAD. The kernel is latency-bound on
//     per-thread dependence structure: epoch2 (48 B gather -> blend -> store)
//     runs at near-zero outstanding bytes. Pairing pixels t and t+NP/2 doubles
//     per-wave memory-level parallelism and overlaps one pixel's gather wait
//     with the other's gate math. Both halves stay fully coalesced.

#define KFRAG 8

typedef int   ivec4 __attribute__((ext_vector_type(4)));
typedef float fvec4 __attribute__((ext_vector_type(4)));

__global__ __launch_bounds__(256) void soft_shader_kernel(
    const int*   __restrict__ p2f,         // [NP, 8]
    const float* __restrict__ bary,        // [NP, 8, 3]
    const float* __restrict__ zbuf,        // [NP, 8]
    const float* __restrict__ dists,       // [NP, 8]
    const float* __restrict__ face_colors, // [F, 3, 3]
    float*       __restrict__ out,         // [NP, 4]
    int NP)
{
    constexpr float SIGMA_INV = 1.0f / 1e-4f;
    constexpr float GAMMA_INV = 1.0f / 1e-4f;
    constexpr float EPS    = 1e-10f;
    constexpr float ZNEAR  = 1.0f;
    constexpr float ZFAR   = 100.0f;
    constexpr float ZSCALE = 1.0f / (ZFAR - ZNEAR);
    constexpr float ZCUT = -1.2e-3f; // exp(ZCUT*1e4) < 1e-5: negligible weight

    int half = (NP + 1) >> 1;
    int t = blockIdx.x * blockDim.x + threadIdx.x;
    if (t >= half) return;

    int pp[2] = {t, t + half};
    bool act1 = (pp[1] < NP);

    // ---- issue ALL stream loads up front; p2f first (gather address root) ----
    ivec4 f[2][2];
    fvec4 z[2][2], d[2][2];
#pragma unroll
    for (int j = 0; j < 2; ++j) {
        size_t pj = (size_t)((j && !act1) ? pp[0] : pp[j]); // clamp inactive
        const ivec4* p4 = (const ivec4*)p2f + pj * 2;
        f[j][0] = __builtin_nontemporal_load(p4 + 0);
        f[j][1] = __builtin_nontemporal_load(p4 + 1);
    }
#pragma unroll
    for (int j = 0; j < 2; ++j) {
        size_t pj = (size_t)((j && !act1) ? pp[0] : pp[j]);
        const fvec4* zb4 = (const fvec4*)zbuf + pj * 2;
        z[j][0] = __builtin_nontemporal_load(zb4 + 0);
        z[j][1] = __builtin_nontemporal_load(zb4 + 1);
        const fvec4* dd4 = (const fvec4*)dists + pj * 2;
        d[j][0] = __builtin_nontemporal_load(dd4 + 0);
        d[j][1] = __builtin_nontemporal_load(dd4 + 1);
    }

    int fid[2][KFRAG];
#pragma unroll
    for (int j = 0; j < 2; ++j) {
        fid[j][0] = f[j][0].x; fid[j][1] = f[j][0].y;
        fid[j][2] = f[j][0].z; fid[j][3] = f[j][0].w;
        fid[j][4] = f[j][1].x; fid[j][5] = f[j][1].y;
        fid[j][6] = f[j][1].z; fid[j][7] = f[j][1].w;
    }

    // winner = first valid fragment (sorted zbuf -> max zinv among valid)
    int fidw[2], kw[2];
#pragma unroll
    for (int j = 0; j < 2; ++j) {
        fidw[j] = -1; kw[j] = 0;
#pragma unroll
        for (int k = KFRAG - 1; k >= 0; --k)
            if (fid[j][k] >= 0) { fidw[j] = fid[j][k]; kw[j] = k; }
    }

    // ---- issue BOTH winners' bary + color gathers back-to-back ----
    float wb[2][3];
    float fcv[2][9];
#pragma unroll
    for (int j = 0; j < 2; ++j) {
        wb[j][0] = wb[j][1] = wb[j][2] = 0.f;
#pragma unroll
        for (int i = 0; i < 9; ++i) fcv[j][i] = 0.f;
        if (fidw[j] >= 0) {
            const float* bp = bary + (size_t)pp[j] * (KFRAG * 3) + kw[j] * 3;
            wb[j][0] = bp[0]; wb[j][1] = bp[1]; wb[j][2] = bp[2];
            const float* fc = face_colors + (size_t)fidw[j] * 9;
            __builtin_memcpy(&fcv[j][0], fc, 9 * sizeof(float));
        }
    }

    // ---- gate math for both pixels (overlaps the gather round-trips) ----
#pragma unroll
    for (int j = 0; j < 2; ++j) {
        if (j && !act1) break;

        float zb_[KFRAG] = {z[j][0].x, z[j][0].y, z[j][0].z, z[j][0].w,
                            z[j][1].x, z[j][1].y, z[j][1].z, z[j][1].w};
        float dd_[KFRAG] = {d[j][0].x, d[j][0].y, d[j][0].z, d[j][0].w,
                            d[j][1].x, d[j][1].y, d[j][1].z, d[j][1].w};

        float zinv[KFRAG], prob[KFRAG];
        float zmax = EPS;
        float keep = 1.0f;
#pragma unroll
        for (int k = 0; k < KFRAG; ++k) {
            bool v = (fid[j][k] >= 0);
            zinv[k] = v ? ((ZFAR - zb_[k]) * ZSCALE) : 0.0f;
            zmax = fmaxf(zmax, zinv[k]);
            prob[k] = v ? (1.0f / (1.0f + __expf(dd_[k] * SIGMA_INV))) : 0.0f;
            keep *= (1.0f - prob[k]);
        }

        float pw = 0.f, zw = 0.f;
#pragma unroll
        for (int k = KFRAG - 1; k >= 0; --k)
            if (fid[j][k] >= 0) { pw = prob[k]; zw = zinv[k]; }

        float delta = fmaxf(__expf((EPS - zmax) * GAMMA_INV), EPS);
        float denom = delta;
        float r = 0.f, g = 0.f, b = 0.f;

        if (fidw[j] >= 0) {
            float w = pw * __expf((zw - zmax) * GAMMA_INV); // zw==zmax -> 1
            float tr = fmaf(wb[j][0], fcv[j][0], fmaf(wb[j][1], fcv[j][3], wb[j][2] * fcv[j][6]));
            float tg = fmaf(wb[j][0], fcv[j][1], fmaf(wb[j][1], fcv[j][4], wb[j][2] * fcv[j][7]));
            float tb = fmaf(wb[j][0], fcv[j][2], fmaf(wb[j][1], fcv[j][5], wb[j][2] * fcv[j][8]));
            denom += w;
            r = fmaf(w, tr, r);
            g = fmaf(w, tg, g);
            b = fmaf(w, tb, b);
        }

        // rare extra gate-passers (~0.8%/pixel): execz-skipped bodies
#pragma unroll
        for (int k = 0; k < KFRAG; ++k) {
            if ((fid[j][k] >= 0) && (k != kw[j]) && (zinv[k] - zmax > ZCUT)) {
                float w = prob[k] * __expf((zinv[k] - zmax) * GAMMA_INV);
                const float* bp = bary + (size_t)pp[j] * (KFRAG * 3) + k * 3;
                float c0 = bp[0], c1 = bp[1], c2 = bp[2];
                const float* fc = face_colors + (size_t)fid[j][k] * 9;
                float e[9];
                __builtin_memcpy(e, fc, 9 * sizeof(float));
                float tr = fmaf(c0, e[0], fmaf(c1, e[3], c2 * e[6]));
                float tg = fmaf(c0, e[1], fmaf(c1, e[4], c2 * e[7]));
                float tb = fmaf(c0, e[2], fmaf(c1, e[5], c2 * e[8]));
                denom += w;
                r = fmaf(w, tr, r);
                g = fmaf(w, tg, g);
                b = fmaf(w, tb, b);
            }
        }

        float inv = 1.0f / denom;
        fvec4 o;
        o.x = (r + delta) * inv; // background (1,1,1): + delta/denom
        o.y = (g + delta) * inv;
        o.z = (b + delta) * inv;
        o.w = keep;
        __builtin_nontemporal_store(o, (fvec4*)out + pp[j]);
    }
}

extern "C" void kernel_launch(void* const* d_in, const int* in_sizes, int n_in,
                              void* d_out, int out_size, void* d_ws, size_t ws_size,
                              hipStream_t stream) {
    const int*   p2f         = (const int*)d_in[0];
    const float* bary        = (const float*)d_in[1];
    const float* zbuf        = (const float*)d_in[2];
    const float* dists       = (const float*)d_in[3];
    const float* face_colors = (const float*)d_in[4];
    float* out = (float*)d_out;

    int NP = in_sizes[0] / KFRAG; // N*H*W pixels
    int half = (NP + 1) >> 1;
    int block = 256;
    int grid = (half + block - 1) / block;
    soft_shader_kernel<<<grid, block, 0, stream>>>(
        p2f, bary, zbuf, dists, face_colors, out, NP);
}